// Round 3
// baseline (252.326 us; speedup 1.0000x reference)
//
#include <hip/hip_runtime.h>
#include <stdint.h>

#define S_ 2048

typedef __bf16 bf16x8 __attribute__((ext_vector_type(8)));
typedef float f32x4 __attribute__((ext_vector_type(4)));
typedef unsigned int u32x4 __attribute__((ext_vector_type(4)));

union FragU { u32x4 u; bf16x8 v; unsigned short s[8]; };

__device__ __forceinline__ unsigned short f2bf(float f) {
    unsigned int u = __builtin_bit_cast(unsigned int, f);
    u += 0x7fffu + ((u >> 16) & 1u);   // round-to-nearest-even
    return (unsigned short)(u >> 16);
}

__device__ __forceinline__ void gl_lds16(const void* g, void* l) {
    __builtin_amdgcn_global_load_lds(
        (const __attribute__((address_space(1))) unsigned int*)g,
        (__attribute__((address_space(3))) unsigned int*)l, 16, 0, 0);
}

// ---------- Stage 0: weights fp32 -> bf16 (3 x 64x1024) ----------
__global__ __launch_bounds__(256) void cvt_w_kernel(
    const float* __restrict__ wq, const float* __restrict__ wk,
    const float* __restrict__ wv, unsigned short* __restrict__ out)
{
    int i = blockIdx.x * 256 + threadIdx.x;
    int mat = i >> 14;
    int off = (i & 16383) << 2;
    const float* src = (mat == 0) ? wq : (mat == 1) ? wk : wv;
    float4 v = *(const float4*)(src + off);
    ushort4 o;
    o.x = f2bf(v.x); o.y = f2bf(v.y); o.z = f2bf(v.z); o.w = f2bf(v.w);
    *(ushort4*)(out + mat * 65536 + off) = o;
}

// ---------- Stage 0b: mask int32 -> bitmask (64 MB -> 2 MB) ----------
__global__ __launch_bounds__(256) void mask_pack(
    const int* __restrict__ mask, unsigned long long* __restrict__ bits)
{
    int g = blockIdx.x * 256 + threadIdx.x;   // one thread per int
    int m = mask[g];
    unsigned long long b = __ballot(m != 0);  // bit lane = key (g & 63)
    if ((threadIdx.x & 63) == 0) bits[g >> 6] = b;
}

// ---------- Stage 1: projections, m97-style staged MFMA GEMM ----------
// block = 256 thr = 4 waves; 16 rows x 64 cols per block; BK=64, 16 K-steps.
// W staged async via global_load_lds with XOR-swizzled source cols
// (conflict-free B-frag reads without padding). X staged via VGPR with
// fp32->bf16 convert-once into pad-72 LDS (2-way bank = free).
__global__ __launch_bounds__(256) void proj_kernel(
    const float* __restrict__ Q, const float* __restrict__ K, const float* __restrict__ V,
    const unsigned short* __restrict__ Wb,
    const float* __restrict__ Bq, const float* __restrict__ Bk, const float* __restrict__ Bv,
    unsigned short* __restrict__ Qb, unsigned short* __restrict__ Kb,
    unsigned short* __restrict__ Vt)            // Vt: [B][64][S]
{
    const int tid = threadIdx.x;
    const int w = tid >> 6, lane = tid & 63;
    const int lm = lane & 15, quad = lane >> 4;
    const int mat = blockIdx.y;
    const int row0 = blockIdx.x * 16;

    __shared__ unsigned short Xs[16 * 72];      // bf16, pad 64->72
    __shared__ unsigned short Ws[64 * 64];      // bf16, xor-swizzled cols

    const float* X    = (mat == 0) ? Q  : (mat == 1) ? K  : V;
    const float* Bias = (mat == 0) ? Bq : (mat == 1) ? Bk : Bv;
    const unsigned short* W = Wb + mat * 65536;

    f32x4 acc = {0.f, 0.f, 0.f, 0.f};

    // X staging: thread -> (row tid>>4, 4 floats at col (tid&15)*4); lane-contiguous.
    const int xr = tid >> 4;
    const int xc = (tid & 15) * 4;
    const float* xg = X + (row0 + xr) * 1024 + xc;
    unsigned short* xl = &Xs[xr * 72 + xc];

    // W async staging: wave w stages rows [w*16, w*16+16) as 2 insts of 8 rows.
    // LDS slot (row, cg) holds global col-group cg ^ (row&7).
    const int wrr = lane >> 3;                   // 0..7 row-in-group
    const int wcg = (lane & 7) ^ wrr;            // swizzled source col-group
    const unsigned short* wg0 = W + (w * 16 + wrr) * 1024 + wcg * 8;
    const unsigned short* wg1 = W + (w * 16 + 8 + wrr) * 1024 + wcg * 8;
    unsigned short* wl0 = &Ws[(w * 16) * 64];
    unsigned short* wl1 = &Ws[(w * 16 + 8) * 64];

    for (int s = 0; s < 16; ++s) {
        const int k0 = s * 64;
        gl_lds16(wg0 + k0, wl0);
        gl_lds16(wg1 + k0, wl1);
        float4 xv = *(const float4*)(xg + k0);
        ushort4 xb;
        xb.x = f2bf(xv.x); xb.y = f2bf(xv.y); xb.z = f2bf(xv.z); xb.w = f2bf(xv.w);
        *(ushort4*)xl = xb;
        __syncthreads();     // drains vmcnt+lgkmcnt before LDS reads
        #pragma unroll
        for (int h = 0; h < 2; ++h) {
            FragU af, bfr;
            af.u = *(const u32x4*)&Xs[lm * 72 + h * 32 + quad * 8];
            const int cg = (quad + 4 * h) ^ (lm & 7);
            bfr.u = *(const u32x4*)&Ws[(w * 16 + lm) * 64 + cg * 8];
            acc = __builtin_amdgcn_mfma_f32_16x16x32_bf16(af.v, bfr.v, acc, 0, 0, 0);
        }
        __syncthreads();     // WAR: next staging overwrites
    }

    // Epilogue: lane holds C[row=quad*4+r][col=lm] for cols w*16+lm.
    const int col = w * 16 + lm;
    const float bias = Bias[col];
    if (mat == 2) {
        ushort4 vv;
        unsigned short* vs = (unsigned short*)&vv;
        #pragma unroll
        for (int r = 0; r < 4; ++r) vs[r] = f2bf(acc[r] + bias);
        *(ushort4*)&Vt[(row0 >> 11) * 131072 + col * 2048 + (row0 & 2047) + quad * 4] = vv;
    } else {
        unsigned short* dst = (mat == 0) ? Qb : Kb;
        #pragma unroll
        for (int r = 0; r < 4; ++r)
            dst[(row0 + quad * 4 + r) * 64 + col] = f2bf(acc[r] + bias);
    }
}

// ---------- Stage 2: masked attention, no-max softmax ----------
// grid (128 qtiles, 4 batch, 2 key-chunks), 256 thr = 4 waves.
// Wave w: keys [kc*1024 + w*256, +256). p = mask_bit ? exp(s/8) : 0 —
// exact vs reference softmax (scores bounded ~|5|), no cross-lane ops in loop.
__global__ __launch_bounds__(256) void attn_kernel(
    const unsigned short* __restrict__ Qb, const unsigned short* __restrict__ Kb,
    const unsigned short* __restrict__ Vt, const unsigned long long* __restrict__ bits,
    float* __restrict__ O0out, float* __restrict__ O1part, float* __restrict__ lpart)
{
    const int tid = threadIdx.x;
    const int w = tid >> 6, lane = tid & 63;
    const int lm = lane & 15, quad = lane >> 4;
    const int q0 = blockIdx.x * 16;
    const int b = blockIdx.y;
    const int kc = blockIdx.z;

    __shared__ unsigned short Plds[4][16 * 72];   // stride 72: 2-way = free
    __shared__ float Olds[4][1024];
    __shared__ float llds[4][16];

    FragU qf0, qf1;
    const unsigned short* qptr = Qb + (b * 2048 + q0 + lm) * 64 + quad * 8;
    qf0.u = *(const u32x4*)qptr;
    qf1.u = *(const u32x4*)(qptr + 32);

    f32x4 o[4];
    #pragma unroll
    for (int dt = 0; dt < 4; ++dt) { f32x4 z = {0.f,0.f,0.f,0.f}; o[dt] = z; }
    float lsum[4] = {0.f, 0.f, 0.f, 0.f};

    const int k00 = kc * 1024 + w * 256;
    const unsigned long long* bb = bits + (b * 2048 + q0) * 32;
    const unsigned short* kbase = Kb + b * 2048 * 64;
    const unsigned short* vbase = Vt + b * 131072;

    #pragma unroll
    for (int iter = 0; iter < 4; ++iter) {
        const int k0 = k00 + iter * 64;
        const int kb6 = k0 >> 6;

        f32x4 sc[4];
        #pragma unroll
        for (int ct = 0; ct < 4; ++ct) {
            const unsigned short* kptr = kbase + (k0 + ct * 16 + lm) * 64 + quad * 8;
            FragU kf0, kf1;
            kf0.u = *(const u32x4*)kptr;
            kf1.u = *(const u32x4*)(kptr + 32);
            f32x4 a = {0.f,0.f,0.f,0.f};
            a = __builtin_amdgcn_mfma_f32_16x16x32_bf16(qf0.v, kf0.v, a, 0, 0, 0);
            a = __builtin_amdgcn_mfma_f32_16x16x32_bf16(qf1.v, kf1.v, a, 0, 0, 0);
            sc[ct] = a;
        }

        unsigned long long mb[4];
        #pragma unroll
        for (int r = 0; r < 4; ++r) mb[r] = bb[(quad * 4 + r) * 32 + kb6];

        #pragma unroll
        for (int ct = 0; ct < 4; ++ct) {
            #pragma unroll
            for (int r = 0; r < 4; ++r) {
                float p = ((mb[r] >> (ct * 16 + lm)) & 1ull)
                          ? __expf(sc[ct][r] * 0.125f) : 0.f;
                sc[ct][r] = p;
                lsum[r] += p;
            }
        }

        #pragma unroll
        for (int ct = 0; ct < 4; ++ct)
            #pragma unroll
            for (int r = 0; r < 4; ++r)
                Plds[w][(quad * 4 + r) * 72 + ct * 16 + lm] = f2bf(sc[ct][r]);

        #pragma unroll
        for (int ks = 0; ks < 2; ++ks) {
            FragU pf;
            pf.u = *(const u32x4*)&Plds[w][lm * 72 + ks * 32 + quad * 8];
            #pragma unroll
            for (int dt = 0; dt < 4; ++dt) {
                FragU vf;
                vf.u = *(const u32x4*)(vbase + (dt * 16 + lm) * 2048 + k0 + ks * 32 + quad * 8);
                o[dt] = __builtin_amdgcn_mfma_f32_16x16x32_bf16(pf.v, vf.v, o[dt], 0, 0, 0);
            }
        }
    }

    // one-time l reduce over the 16-lane row groups
    #pragma unroll
    for (int r = 0; r < 4; ++r)
        #pragma unroll
        for (int off = 1; off <= 8; off <<= 1)
            lsum[r] += __shfl_xor(lsum[r], off, 64);

    #pragma unroll
    for (int dt = 0; dt < 4; ++dt)
        #pragma unroll
        for (int r = 0; r < 4; ++r)
            Olds[w][(quad * 4 + r) * 64 + dt * 16 + lm] = o[dt][r];
    if (lm == 0)
        #pragma unroll
        for (int r = 0; r < 4; ++r) llds[w][quad * 4 + r] = lsum[r];
    __syncthreads();

    // block-sum the 4 wave partials; chunk 0 -> out buffer, chunk 1 -> ws
    float* Odst = (kc == 0) ? O0out : O1part;
    const int blk = b * 128 + blockIdx.x;        // 0..511
    #pragma unroll
    for (int i = 0; i < 4; ++i) {
        int e = i * 256 + tid;
        Odst[blk * 1024 + e] = Olds[0][e] + Olds[1][e] + Olds[2][e] + Olds[3][e];
    }
    if (tid < 16)
        lpart[(kc * 512 + blk) * 16 + tid] =
            llds[0][tid] + llds[1][tid] + llds[2][tid] + llds[3][tid];
}

// ---------- Stage 3: merge the two key-chunks, normalize ----------
__global__ __launch_bounds__(256) void attn_merge(
    float* __restrict__ out, const float* __restrict__ O1,
    const float* __restrict__ lpart)
{
    int idx = blockIdx.x * 256 + threadIdx.x;   // one f32x4 per thread
    int e4 = idx * 4;
    int blk = e4 >> 10;
    int q = (e4 >> 6) & 15;
    float l = lpart[blk * 16 + q] + lpart[(512 + blk) * 16 + q];
    float inv = 1.f / l;
    float4 a = *(const float4*)&out[e4];
    float4 c = *(const float4*)&O1[e4];
    float4 r;
    r.x = (a.x + c.x) * inv; r.y = (a.y + c.y) * inv;
    r.z = (a.z + c.z) * inv; r.w = (a.w + c.w) * inv;
    *(float4*)&out[e4] = r;
}

extern "C" void kernel_launch(void* const* d_in, const int* in_sizes, int n_in,
                              void* d_out, int out_size, void* d_ws, size_t ws_size,
                              hipStream_t stream) {
    const float* Q   = (const float*)d_in[0];
    const float* K   = (const float*)d_in[1];
    const float* V   = (const float*)d_in[2];
    const int* mask  = (const int*)d_in[3];
    const float* Wq  = (const float*)d_in[4];
    const float* bq  = (const float*)d_in[5];
    const float* Wk  = (const float*)d_in[6];
    const float* bk  = (const float*)d_in[7];
    const float* Wv  = (const float*)d_in[8];
    const float* bv  = (const float*)d_in[9];
    float* out = (float*)d_out;

    char* ws = (char*)d_ws;
    unsigned short* Qb = (unsigned short*)(ws);                          // 1 MB
    unsigned short* Kb = (unsigned short*)(ws + (1u << 20));             // 1 MB
    unsigned short* Vt = (unsigned short*)(ws + (2u << 20));             // 1 MB
    unsigned short* Wb = (unsigned short*)(ws + (3u << 20));             // 384 KB
    unsigned long long* bits = (unsigned long long*)(ws + 3584u * 1024); // 2 MB @3.5M
    float* O1part = (float*)(ws + 5632u * 1024);                         // 2 MB @5.5M
    float* lpart  = (float*)(ws + 7680u * 1024);                         // 64 KB @7.5M

    hipLaunchKernelGGL(cvt_w_kernel, dim3(192), dim3(256), 0, stream, Wq, Wk, Wv, Wb);
    hipLaunchKernelGGL(mask_pack, dim3(65536), dim3(256), 0, stream, mask, bits);
    hipLaunchKernelGGL(proj_kernel, dim3(512, 3), dim3(256), 0, stream,
                       Q, K, V, Wb, bq, bk, bv, Qb, Kb, Vt);
    hipLaunchKernelGGL(attn_kernel, dim3(128, 4, 2), dim3(256), 0, stream,
                       Qb, Kb, Vt, bits, out, O1part, lpart);
    hipLaunchKernelGGL(attn_merge, dim3(512), dim3(256), 0, stream,
                       out, O1part, lpart);
}